// Round 6
// baseline (3991.909 us; speedup 1.0000x reference)
//
#include <hip/hip_runtime.h>
#include <hip/hip_bf16.h>
#include <math.h>

#define N_POOL 2048
#define D_POOL 4608

typedef __hip_bfloat16 bf16;

// input indices
#define IX 0
#define IPOOL 1
#define IAW0 2
#define IAB0 3
#define IAW1 4
#define IAB1 5
#define IWQ 6
#define IWK 7
#define ILOG 8
#define ITAU 9
#define IWBASE 10
#define IBBASE 11
#define IGAMMA 12
#define ILNS 13
#define ILNB 14
#define IBW0 15
#define IBB0 16
#define IBW1 17
#define IBB1 18

// ---------- helpers ----------
__device__ inline float wsum(float v) {
#pragma unroll
    for (int off = 32; off > 0; off >>= 1) v += __shfl_xor(v, off, 64);
    return v;
}
// dual-mode input load: f=1 -> bf16, f=0 -> fp32
__device__ inline float ldin(const void* p, size_t i, int f) {
    if (f) return __bfloat162float(((const bf16*)p)[i]);
    return ((const float*)p)[i];
}
__device__ inline float gelu_f(float x) {
    float t = tanhf(0.7978845608028654f * (x + 0.044715f * x * x * x));
    return 0.5f * x * (1.0f + t);
}

// ---------- per-input dtype detector (insurance; inputs look all-fp32) ----------
struct P19 { const void* p[19]; long n[19]; };

__global__ void detect_all(P19 ip, int* flags) {
    const int j = blockIdx.x;
    const unsigned short* u = (const unsigned short*)ip.p[j];
    long nelem = ip.n[j];
    long nhalf = nelem >> 1; if (nhalf < 1) nhalf = 1;
    long kstep = (nhalf + 65535) >> 16; if (kstep < 1) kstep = 1;
    int W = 0, S = 0, Z = 0, O = 0, C = 0;
    for (long k = threadIdx.x; k * kstep < nhalf; k += 256) {
        long i = k * kstep * 2;
        unsigned short ev = u[i], od = u[i + 1];
        int e = (ev >> 7) & 0xFF;
        if (ev == 0) Z++;
        else if (e >= 90 && e <= 141) S++;
        else W++;
        if (od) O++;
        C++;
    }
    __shared__ int sw[256], ss[256], sz[256], so[256], sc[256];
    sw[threadIdx.x] = W; ss[threadIdx.x] = S; sz[threadIdx.x] = Z;
    so[threadIdx.x] = O; sc[threadIdx.x] = C;
    __syncthreads();
    if (threadIdx.x == 0) {
        int tw = 0, ts = 0, tz = 0, to = 0, tc = 0;
        for (int i = 0; i < 256; i++) {
            tw += sw[i]; ts += ss[i]; tz += sz[i]; to += so[i]; tc += sc[i];
        }
        int f;
        if (tw * 16 > tc) f = 0;                            // wild exponents: fp32
        else if (ts == 0 && tw == 0) f = (to > 0) ? 0 : 1;  // const fp32 vs zeros
        else f = (ts >= tz) ? 1 : 0;
        flags[j] = f;
    }
}

// ---------- generic 64x64 tiled GEMM: C = act(A@B(^T) + bias), fp32 out ----------
// afi/bfi/bifi: flags index for external inputs, -1 for fp32 scratch.
template <int TRANSB>
__global__ __launch_bounds__(256) void gemm64(
    const void* __restrict__ A, int lda, int afi,
    const void* __restrict__ B, int ldb, int bfi, size_t boffs,
    const void* __restrict__ bias, int bifi,
    float* __restrict__ C, int ldc,
    int M, int N, int K, int act, const int* __restrict__ flags)
{
    const int fa = (afi >= 0) ? flags[afi] : 0;
    const int fb = (bfi >= 0) ? flags[bfi] : 0;
    const int fbias = (bifi >= 0) ? flags[bifi] : 0;
    __shared__ float As[16][65];
    __shared__ float Bs[16][65];
    const int tid = threadIdx.x;
    const int tx = tid & 15, ty = tid >> 4;
    const int bx = blockIdx.x, by = blockIdx.y;
    float acc[4][4] = {};
    for (int k0 = 0; k0 < K; k0 += 16) {
#pragma unroll
        for (int i = 0; i < 4; i++) {
            int idx = tid + i * 256;
            int m = idx >> 4, kk = idx & 15;
            As[kk][m] = ldin(A, (size_t)(by * 64 + m) * lda + k0 + kk, fa);
        }
#pragma unroll
        for (int i = 0; i < 4; i++) {
            int idx = tid + i * 256;
            if (TRANSB) {
                int nn2 = idx >> 4, kk = idx & 15;
                Bs[kk][nn2] = ldin(B, boffs + (size_t)(bx * 64 + nn2) * ldb + k0 + kk, fb);
            } else {
                int kk = idx >> 6, nn2 = idx & 63;
                Bs[kk][nn2] = ldin(B, boffs + (size_t)(k0 + kk) * ldb + bx * 64 + nn2, fb);
            }
        }
        __syncthreads();
#pragma unroll
        for (int kk = 0; kk < 16; kk++) {
            float av[4], bv[4];
#pragma unroll
            for (int i = 0; i < 4; i++) av[i] = As[kk][ty * 4 + i];
#pragma unroll
            for (int j = 0; j < 4; j++) bv[j] = Bs[kk][tx * 4 + j];
#pragma unroll
            for (int i = 0; i < 4; i++)
#pragma unroll
                for (int j = 0; j < 4; j++) acc[i][j] += av[i] * bv[j];
        }
        __syncthreads();
    }
#pragma unroll
    for (int i = 0; i < 4; i++) {
        int m = by * 64 + ty * 4 + i;
#pragma unroll
        for (int j = 0; j < 4; j++) {
            int n = bx * 64 + tx * 4 + j;
            float v = acc[i][j];
            if (bias) v += ldin(bias, n, fbias);
            if (act == 1) v = gelu_f(v);
            C[(size_t)m * ldc + n] = v;
        }
    }
}

// ---------- keys GEMM + fused normalize (fp32 outputs) ----------
__global__ __launch_bounds__(256) void keys_kernel(
    const void* __restrict__ pool, const void* __restrict__ W_K,
    const int* __restrict__ flags,
    float* __restrict__ keys_out, float* __restrict__ kn)
{
    const int fp = flags[IPOOL], fk = flags[IWK];
    __shared__ float As[16][65];
    __shared__ float Bs[16][65];
    const int tid = threadIdx.x;
    const int tx = tid & 15, ty = tid >> 4;
    const int a = blockIdx.x, by = blockIdx.y;
    float acc[4][4] = {};
    for (int k0 = 0; k0 < 4608; k0 += 16) {
#pragma unroll
        for (int i = 0; i < 4; i++) {
            int idx = tid + i * 256;
            int m = idx >> 4, kk = idx & 15;
            As[kk][m] = ldin(pool, (size_t)(by * 64 + m) * 4608 + k0 + kk, fp);
        }
#pragma unroll
        for (int i = 0; i < 4; i++) {
            int idx = tid + i * 256;
            int kk = idx >> 6, nn2 = idx & 63;
            Bs[kk][nn2] = ldin(W_K, (size_t)a * 294912 + (size_t)(k0 + kk) * 64 + nn2, fk);
        }
        __syncthreads();
#pragma unroll
        for (int kk = 0; kk < 16; kk++) {
            float av[4], bv[4];
#pragma unroll
            for (int i = 0; i < 4; i++) av[i] = As[kk][ty * 4 + i];
#pragma unroll
            for (int j = 0; j < 4; j++) bv[j] = Bs[kk][tx * 4 + j];
#pragma unroll
            for (int i = 0; i < 4; i++)
#pragma unroll
                for (int j = 0; j < 4; j++) acc[i][j] += av[i] * bv[j];
        }
        __syncthreads();
    }
#pragma unroll
    for (int i = 0; i < 4; i++) {
        float ss = acc[i][0] * acc[i][0] + acc[i][1] * acc[i][1]
                 + acc[i][2] * acc[i][2] + acc[i][3] * acc[i][3];
#pragma unroll
        for (int off = 8; off > 0; off >>= 1) ss += __shfl_xor(ss, off, 64);
        float inv = 1.f / (sqrtf(ss) + 1e-8f);
        int m = by * 64 + ty * 4 + i;
        int col = a * 64 + tx * 4;
#pragma unroll
        for (int j = 0; j < 4; j++) {
            keys_out[(size_t)m * 256 + col + j] = acc[i][j];
            kn[(size_t)m * 256 + col + j] = acc[i][j] * inv;
        }
    }
}

// ---------- softmax over 4 aspect logits ----------
__global__ void softmax4_kernel(const void* __restrict__ logits,
                                const int* __restrict__ flags, float* __restrict__ w) {
    if (threadIdx.x == 0) {
        int f = flags[ILOG];
        float l0 = ldin(logits, 0, f), l1 = ldin(logits, 1, f);
        float l2 = ldin(logits, 2, f), l3 = ldin(logits, 3, f);
        float m = fmaxf(fmaxf(l0, l1), fmaxf(l2, l3));
        float e0 = expf(l0 - m), e1 = expf(l1 - m), e2 = expf(l2 - m), e3 = expf(l3 - m);
        float s = e0 + e1 + e2 + e3;
        w[0] = e0 / s; w[1] = e1 / s; w[2] = e2 / s; w[3] = e3 / s;
    }
}

// ---------- queries: normalized, aspect-weight folded ----------
__global__ __launch_bounds__(256) void queries_kernel(
    const float* __restrict__ hA, const void* __restrict__ W_Q,
    const int* __restrict__ flags, const float* __restrict__ w, float* __restrict__ qw)
{
    const int f = flags[IWQ];
    const int b = blockIdx.x;
    const int a = threadIdx.x >> 6, q = threadIdx.x & 63;
    const float* ha = hA + b * 256;
    float s = 0.f;
#pragma unroll 4
    for (int d = 0; d < 256; d++)
        s += ha[d] * ldin(W_Q, (size_t)a * 16384 + (size_t)d * 64 + q, f);
    float nrm = sqrtf(wsum(s * s));
    qw[b * 256 + a * 64 + q] = s / (nrm + 1e-8f) * w[a];
}

// ---------- alpha: writes fp32 alpha (output) + fp32 alphaT (scratch) ----------
__global__ __launch_bounds__(256) void alpha_kernel(
    const float* __restrict__ scores, const void* __restrict__ tau_p,
    const int* __restrict__ flags,
    float* __restrict__ alpha_out, float* __restrict__ alphaT)
{
    const int b = blockIdx.x;
    const int tid = threadIdx.x;
    const float tauv = ldin(tau_p, 0, flags[ITAU]);
    float ar[8];
    float lsum = 0.f;
#pragma unroll
    for (int i = 0; i < 8; i++) {
        int n = i * 256 + tid;
        float s = scores[b * 2048 + n];
        float g = 1.f / (1.f + expf(-(s - tauv)));  // LAMBDA_SHARP=1
        ar[i] = g * expf(s);                         // TEMPERATURE=1
        lsum += ar[i];
    }
    __shared__ float sb[4];
    float wsv = wsum(lsum);
    if ((tid & 63) == 0) sb[tid >> 6] = wsv;
    __syncthreads();
    float tot = sb[0] + sb[1] + sb[2] + sb[3];
    float inv = 1.f / (tot + 1e-8f);
#pragma unroll
    for (int i = 0; i < 8; i++) {
        int n = i * 256 + tid;
        float al = ar[i] * inv;
        alpha_out[b * 2048 + n] = al;
        alphaT[(size_t)n * 256 + b] = al;
    }
}

// ---------- W_assembled[b,d,e] = W_base[d,e] + sum_n alpha[b,n]*UV[n,d,e] ----------
__global__ __launch_bounds__(256) void assemble_kernel(
    const float* __restrict__ alphaT,   // (2048,256) [n][b]
    const void* __restrict__ pool,      // (2048,4608)
    const void* __restrict__ W_base,    // (256,256)
    const int* __restrict__ flags,
    float* __restrict__ Wout)           // (256,256,256) [b][d][e] fp32
{
    const int fp = flags[IPOOL], fw = flags[IWBASE];
    const int et = blockIdx.x, dt = blockIdx.y, bt = blockIdx.z;
    const int tid = threadIdx.x;
    const int tx = tid & 15, ty = tid >> 4;
    __shared__ float u_s[64], v_s[256], uv_s[256];
    float acc[4][16] = {};
    const int b0 = bt * 64;
    const int dloc = tid >> 5, eloc = tid & 31;
    for (int n = 0; n < N_POOL; n++) {
        const size_t prow = (size_t)n * D_POOL;
        float4 av = ((const float4*)(alphaT + (size_t)n * 256 + b0))[ty];
        v_s[tid] = ldin(pool, prow + 2048 + dloc * 256 + et * 32 + eloc, fp);
        if (tid < 64) u_s[tid] = ldin(pool, prow + dt * 64 + tid, fp);
        __syncthreads();
        float uvv = 0.f;
#pragma unroll
        for (int r = 0; r < 8; r++) uvv += u_s[dloc * 8 + r] * v_s[r * 32 + eloc];
        uv_s[tid] = uvv;  // UV at (d=dt*8+(tid>>5), e=et*32+(tid&31))
        __syncthreads();
#pragma unroll
        for (int j = 0; j < 16; j++) {
            float u = uv_s[j * 16 + tx];
            acc[0][j] += av.x * u;
            acc[1][j] += av.y * u;
            acc[2][j] += av.z * u;
            acc[3][j] += av.w * u;
        }
        __syncthreads();
    }
#pragma unroll
    for (int j = 0; j < 16; j++) {
        int c = j * 16 + tx;
        int d = dt * 8 + (c >> 5);
        int e = et * 32 + (c & 31);
        float wb = ldin(W_base, d * 256 + e, fw);
#pragma unroll
        for (int i = 0; i < 4; i++) {
            int b = b0 + ty * 4 + i;
            Wout[((size_t)b * 256 + d) * 256 + e] = acc[i][j] + wb;
        }
    }
}

// ---------- h_t + y (reads fp32 W_assembled) ----------
__global__ __launch_bounds__(256) void hty_kernel(
    const float* __restrict__ Wout, const float* __restrict__ hA,
    const float* __restrict__ bass, const void* __restrict__ gamma_p,
    const int* __restrict__ flags, float* __restrict__ y)
{
    const int b = blockIdx.y;
    const int c = blockIdx.x * 4 + (threadIdx.x >> 6);
    const int lane = threadIdx.x & 63;
    const float4 wv = ((const float4*)(Wout + ((size_t)b * 65536 + c * 256)))[lane];
    const float4 h4 = ((const float4*)(hA + b * 256))[lane];
    float s = wv.x * h4.x + wv.y * h4.y + wv.z * h4.z + wv.w * h4.w;
    s = wsum(s);
    if (lane == 0) {
        float ht = s + bass[b * 256 + c];
        y[b * 256 + c] = hA[b * 256 + c] + ldin(gamma_p, 0, flags[IGAMMA]) * ht;
    }
}

// ---------- layernorm ----------
__global__ __launch_bounds__(256) void ln_kernel(
    const float* __restrict__ y, const void* __restrict__ ln_scale,
    const void* __restrict__ ln_bias, const int* __restrict__ flags,
    float* __restrict__ hmid)
{
    const int fs = flags[ILNS], fb = flags[ILNB];
    const int b = blockIdx.x, tid = threadIdx.x;
    float v = y[b * 256 + tid];
    __shared__ float s1b[4], s2b[4];
    float w1 = wsum(v), w2 = wsum(v * v);
    if ((tid & 63) == 0) { s1b[tid >> 6] = w1; s2b[tid >> 6] = w2; }
    __syncthreads();
    float mu = (s1b[0] + s1b[1] + s1b[2] + s1b[3]) * (1.f / 256.f);
    float ex2 = (s2b[0] + s2b[1] + s2b[2] + s2b[3]) * (1.f / 256.f);
    float var = ex2 - mu * mu;
    float inv = 1.f / sqrtf(var + 1e-6f);
    hmid[b * 256 + tid] = (v - mu) * inv * ldin(ln_scale, tid, fs)
                        + ldin(ln_bias, tid, fb);
}

// ---------- launch ----------
extern "C" void kernel_launch(void* const* d_in, const int* in_sizes, int n_in,
                              void* d_out, int out_size, void* d_ws, size_t ws_size,
                              hipStream_t stream)
{
    (void)out_size; (void)n_in;
    const void* x      = d_in[0];
    const void* pool   = d_in[1];
    const void* A_w0   = d_in[2];
    const void* A_b0   = d_in[3];
    const void* A_w1   = d_in[4];
    const void* A_b1   = d_in[5];
    const void* W_Q    = d_in[6];
    const void* W_K    = d_in[7];
    const void* logits = d_in[8];
    const void* tau    = d_in[9];
    const void* W_base = d_in[10];
    const void* b_base = d_in[11];
    const void* gamma  = d_in[12];
    const void* ln_s   = d_in[13];
    const void* ln_b   = d_in[14];
    const void* B_w0   = d_in[15];
    const void* B_b0   = d_in[16];
    const void* B_w1   = d_in[17];
    const void* B_b1   = d_in[18];

    // Outputs: FP32 (reference returns float32), concatenated in return order.
    float* out       = (float*)d_out;
    float* out0      = out;               // (256,512)    = 131072
    float* out_alpha = out + 131072;      // (256,2048)   = 524288
    float* out_W     = out + 655360;      // (256,256,256)= 16777216
    float* out_keys  = out + 17432576;    // (2048,4,64)  = 524288

    // Small scratch, always in d_ws
    float* ws = (float*)d_ws;
    int*   flagp   = (int*)d_ws;      // ints [0,32)
    float* ws_w    = ws + 32;         // 4
    float* ws_hA   = ws + 64;         // 65536
    float* ws_qw   = ws + 65600;      // 65536
    float* ws_bass = ws + 131136;     // 65536
    float* ws_y    = ws + 196672;     // 65536
    float* ws_hmid = ws + 262208;     // 65536 -> 327744

    // Big slots: prefer d_ws (7.6 MB total); fall back to out_W region
    // (16.7M floats; all tenants dead before assemble writes it).
    size_t wsf = ws_size / 4;
    bool full = wsf >= 1900608;
    float* slotA;   // G -> scores -> T1
    float* slotB;   // kn
    float* alphaT;
    float* T1;
    float* scr = (float*)out_W;
    if (full) {
        slotA  = ws + 327744;   // 524288
        slotB  = ws + 852032;   // 524288
        alphaT = ws + 1376320;  // 524288 -> 1900608 floats total
        T1     = slotA;
    } else {
        alphaT = ws + 327744;   // needs ws >= 3.41 MB
        slotA  = scr;
        slotB  = scr + 524288;
        T1     = alphaT;        // alphaT dead after assemble
    }
    float* G      = slotA;
    float* scores = slotA;
    float* kn     = slotB;

    // 0) per-input dtype detection (expected: all fp32)
    P19 ip;
    for (int i = 0; i < 19; i++) { ip.p[i] = d_in[i]; ip.n[i] = in_sizes[i]; }
    detect_all<<<19, 256, 0, stream>>>(ip, flagp);
    // 1) aspect softmax
    softmax4_kernel<<<1, 64, 0, stream>>>(logits, flagp, ws_w);
    // 2) A-MLP
    gemm64<0><<<dim3(16, 4), 256, 0, stream>>>(
        x, 512, IX, A_w0, 1024, IAW0, 0, A_b0, IAB0,
        G, 1024, 256, 1024, 512, 1, flagp);
    gemm64<0><<<dim3(4, 4), 256, 0, stream>>>(
        G, 1024, -1, A_w1, 256, IAW1, 0, A_b1, IAB1,
        ws_hA, 256, 256, 256, 1024, 0, flagp);
    // 3) keys + normalize
    keys_kernel<<<dim3(4, 32), 256, 0, stream>>>(pool, W_K, flagp, out_keys, kn);
    // 4) queries
    queries_kernel<<<256, 256, 0, stream>>>(ws_hA, W_Q, flagp, ws_w, ws_qw);
    // 5) scores = qw @ kn^T
    gemm64<1><<<dim3(32, 4), 256, 0, stream>>>(
        ws_qw, 256, -1, kn, 256, -1, 0, nullptr, -1,
        scores, 2048, 256, 2048, 256, 0, flagp);
    // 6) alpha -> out_alpha (fp32 output doubles as scratch) + alphaT
    alpha_kernel<<<256, 256, 0, stream>>>(scores, tau, flagp, out_alpha, alphaT);
    // 7) b_assembled = alpha @ pool[:,4096:4352] + b_base (before assemble)
    gemm64<0><<<dim3(4, 4), 256, 0, stream>>>(
        out_alpha, 2048, -1, pool, 4608, IPOOL, 4096, b_base, IBBASE,
        ws_bass, 256, 256, 256, 2048, 0, flagp);
    // 8) W_assembled (dominant)
    assemble_kernel<<<dim3(8, 32, 4), 256, 0, stream>>>(alphaT, pool, W_base, flagp, out_W);
    // 9) h_t, y
    hty_kernel<<<dim3(64, 256), 256, 0, stream>>>(out_W, ws_hA, ws_bass, gamma, flagp, ws_y);
    // 10) layernorm
    ln_kernel<<<256, 256, 0, stream>>>(ws_y, ln_s, ln_b, flagp, ws_hmid);
    // 11) B-MLP
    gemm64<0><<<dim3(16, 4), 256, 0, stream>>>(
        ws_hmid, 256, -1, B_w0, 1024, IBW0, 0, B_b0, IBB0,
        T1, 1024, 256, 1024, 256, 1, flagp);
    gemm64<0><<<dim3(8, 4), 256, 0, stream>>>(
        T1, 1024, -1, B_w1, 512, IBW1, 0, B_b1, IBB1,
        out0, 512, 256, 512, 1024, 0, flagp);
}

// Round 7
// 2155.707 us; speedup vs baseline: 1.8518x; 1.8518x over previous
//
#include <hip/hip_runtime.h>
#include <hip/hip_bf16.h>
#include <math.h>

#define N_POOL 2048
#define D_POOL 4608

typedef __hip_bfloat16 bf16;
typedef __attribute__((ext_vector_type(8))) short bf16x8;
typedef __attribute__((ext_vector_type(4))) float f32x4;

// input indices
#define IX 0
#define IPOOL 1
#define IAW0 2
#define IAB0 3
#define IAW1 4
#define IAB1 5
#define IWQ 6
#define IWK 7
#define ILOG 8
#define ITAU 9
#define IWBASE 10
#define IBBASE 11
#define IGAMMA 12
#define ILNS 13
#define ILNB 14
#define IBW0 15
#define IBB0 16
#define IBW1 17
#define IBB1 18

// ---------- helpers ----------
__device__ inline float wsum(float v) {
#pragma unroll
    for (int off = 32; off > 0; off >>= 1) v += __shfl_xor(v, off, 64);
    return v;
}
__device__ inline float ldin(const void* p, size_t i, int f) {
    if (f) return __bfloat162float(((const bf16*)p)[i]);
    return ((const float*)p)[i];
}
__device__ inline float gelu_f(float x) {
    float t = tanhf(0.7978845608028654f * (x + 0.044715f * x * x * x));
    return 0.5f * x * (1.0f + t);
}
__device__ inline unsigned short bfbits(float f) {
    __hip_bfloat16 h = __float2bfloat16(f);
    return *reinterpret_cast<unsigned short*>(&h);
}

// ---------- per-input dtype detector (insurance; inputs measured all-fp32) ----------
struct P19 { const void* p[19]; long n[19]; };

__global__ void detect_all(P19 ip, int* flags) {
    const int j = blockIdx.x;
    const unsigned short* u = (const unsigned short*)ip.p[j];
    long nelem = ip.n[j];
    long nhalf = nelem >> 1; if (nhalf < 1) nhalf = 1;
    long kstep = (nhalf + 65535) >> 16; if (kstep < 1) kstep = 1;
    int W = 0, S = 0, Z = 0, O = 0, C = 0;
    for (long k = threadIdx.x; k * kstep < nhalf; k += 256) {
        long i = k * kstep * 2;
        unsigned short ev = u[i], od = u[i + 1];
        int e = (ev >> 7) & 0xFF;
        if (ev == 0) Z++;
        else if (e >= 90 && e <= 141) S++;
        else W++;
        if (od) O++;
        C++;
    }
    __shared__ int sw[256], ss[256], sz[256], so[256], sc[256];
    sw[threadIdx.x] = W; ss[threadIdx.x] = S; sz[threadIdx.x] = Z;
    so[threadIdx.x] = O; sc[threadIdx.x] = C;
    __syncthreads();
    if (threadIdx.x == 0) {
        int tw = 0, ts = 0, tz = 0, to = 0, tc = 0;
        for (int i = 0; i < 256; i++) {
            tw += sw[i]; ts += ss[i]; tz += sz[i]; to += so[i]; tc += sc[i];
        }
        int f;
        if (tw * 16 > tc) f = 0;
        else if (ts == 0 && tw == 0) f = (to > 0) ? 0 : 1;
        else f = (ts >= tz) ? 1 : 0;
        flags[j] = f;
    }
}

// ---------- generic 64x64 tiled GEMM: C = act(A@B(^T) + bias), fp32 out ----------
template <int TRANSB>
__global__ __launch_bounds__(256) void gemm64(
    const void* __restrict__ A, int lda, int afi,
    const void* __restrict__ B, int ldb, int bfi, size_t boffs,
    const void* __restrict__ bias, int bifi,
    float* __restrict__ C, int ldc,
    int M, int N, int K, int act, const int* __restrict__ flags)
{
    const int fa = (afi >= 0) ? flags[afi] : 0;
    const int fb = (bfi >= 0) ? flags[bfi] : 0;
    const int fbias = (bifi >= 0) ? flags[bifi] : 0;
    __shared__ __align__(16) float As[16][68];
    __shared__ __align__(16) float Bs[16][68];
    const int tid = threadIdx.x;
    const int tx = tid & 15, ty = tid >> 4;
    const int bx = blockIdx.x, by = blockIdx.y;
    float acc[4][4] = {};
    for (int k0 = 0; k0 < K; k0 += 16) {
#pragma unroll
        for (int i = 0; i < 4; i++) {
            int idx = tid + i * 256;
            int m = idx >> 4, kk = idx & 15;
            As[kk][m] = ldin(A, (size_t)(by * 64 + m) * lda + k0 + kk, fa);
        }
#pragma unroll
        for (int i = 0; i < 4; i++) {
            int idx = tid + i * 256;
            if (TRANSB) {
                int nn2 = idx >> 4, kk = idx & 15;
                Bs[kk][nn2] = ldin(B, boffs + (size_t)(bx * 64 + nn2) * ldb + k0 + kk, fb);
            } else {
                int kk = idx >> 6, nn2 = idx & 63;
                Bs[kk][nn2] = ldin(B, boffs + (size_t)(k0 + kk) * ldb + bx * 64 + nn2, fb);
            }
        }
        __syncthreads();
#pragma unroll
        for (int kk = 0; kk < 16; kk++) {
            float4 av4 = *(const float4*)&As[kk][ty * 4];
            float4 bv4 = *(const float4*)&Bs[kk][tx * 4];
            float av[4] = {av4.x, av4.y, av4.z, av4.w};
            float bv[4] = {bv4.x, bv4.y, bv4.z, bv4.w};
#pragma unroll
            for (int i = 0; i < 4; i++)
#pragma unroll
                for (int j = 0; j < 4; j++) acc[i][j] += av[i] * bv[j];
        }
        __syncthreads();
    }
#pragma unroll
    for (int i = 0; i < 4; i++) {
        int m = by * 64 + ty * 4 + i;
#pragma unroll
        for (int j = 0; j < 4; j++) {
            int n = bx * 64 + tx * 4 + j;
            float v = acc[i][j];
            if (bias) v += ldin(bias, n, fbias);
            if (act == 1) v = gelu_f(v);
            C[(size_t)m * ldc + n] = v;
        }
    }
}

// ---------- keys GEMM + fused normalize (fp32 outputs) ----------
__global__ __launch_bounds__(256) void keys_kernel(
    const void* __restrict__ pool, const void* __restrict__ W_K,
    const int* __restrict__ flags,
    float* __restrict__ keys_out, float* __restrict__ kn)
{
    const int fp = flags[IPOOL], fk = flags[IWK];
    __shared__ __align__(16) float As[16][68];
    __shared__ __align__(16) float Bs[16][68];
    const int tid = threadIdx.x;
    const int tx = tid & 15, ty = tid >> 4;
    const int a = blockIdx.x, by = blockIdx.y;
    float acc[4][4] = {};
    for (int k0 = 0; k0 < 4608; k0 += 16) {
#pragma unroll
        for (int i = 0; i < 4; i++) {
            int idx = tid + i * 256;
            int m = idx >> 4, kk = idx & 15;
            As[kk][m] = ldin(pool, (size_t)(by * 64 + m) * 4608 + k0 + kk, fp);
        }
#pragma unroll
        for (int i = 0; i < 4; i++) {
            int idx = tid + i * 256;
            int kk = idx >> 6, nn2 = idx & 63;
            Bs[kk][nn2] = ldin(W_K, (size_t)a * 294912 + (size_t)(k0 + kk) * 64 + nn2, fk);
        }
        __syncthreads();
#pragma unroll
        for (int kk = 0; kk < 16; kk++) {
            float4 av4 = *(const float4*)&As[kk][ty * 4];
            float4 bv4 = *(const float4*)&Bs[kk][tx * 4];
            float av[4] = {av4.x, av4.y, av4.z, av4.w};
            float bv[4] = {bv4.x, bv4.y, bv4.z, bv4.w};
#pragma unroll
            for (int i = 0; i < 4; i++)
#pragma unroll
                for (int j = 0; j < 4; j++) acc[i][j] += av[i] * bv[j];
        }
        __syncthreads();
    }
#pragma unroll
    for (int i = 0; i < 4; i++) {
        float ss = acc[i][0] * acc[i][0] + acc[i][1] * acc[i][1]
                 + acc[i][2] * acc[i][2] + acc[i][3] * acc[i][3];
#pragma unroll
        for (int off = 8; off > 0; off >>= 1) ss += __shfl_xor(ss, off, 64);
        float inv = 1.f / (sqrtf(ss) + 1e-8f);
        int m = by * 64 + ty * 4 + i;
        int col = a * 64 + tx * 4;
#pragma unroll
        for (int j = 0; j < 4; j++) {
            keys_out[(size_t)m * 256 + col + j] = acc[i][j];
            kn[(size_t)m * 256 + col + j] = acc[i][j] * inv;
        }
    }
}

// ---------- softmax over 4 aspect logits ----------
__global__ void softmax4_kernel(const void* __restrict__ logits,
                                const int* __restrict__ flags, float* __restrict__ w) {
    if (threadIdx.x == 0) {
        int f = flags[ILOG];
        float l0 = ldin(logits, 0, f), l1 = ldin(logits, 1, f);
        float l2 = ldin(logits, 2, f), l3 = ldin(logits, 3, f);
        float m = fmaxf(fmaxf(l0, l1), fmaxf(l2, l3));
        float e0 = expf(l0 - m), e1 = expf(l1 - m), e2 = expf(l2 - m), e3 = expf(l3 - m);
        float s = e0 + e1 + e2 + e3;
        w[0] = e0 / s; w[1] = e1 / s; w[2] = e2 / s; w[3] = e3 / s;
    }
}

// ---------- queries: normalized, aspect-weight folded ----------
__global__ __launch_bounds__(256) void queries_kernel(
    const float* __restrict__ hA, const void* __restrict__ W_Q,
    const int* __restrict__ flags, const float* __restrict__ w, float* __restrict__ qw)
{
    const int f = flags[IWQ];
    const int b = blockIdx.x;
    const int a = threadIdx.x >> 6, q = threadIdx.x & 63;
    const float* ha = hA + b * 256;
    float s = 0.f;
#pragma unroll 4
    for (int d = 0; d < 256; d++)
        s += ha[d] * ldin(W_Q, (size_t)a * 16384 + (size_t)d * 64 + q, f);
    float nrm = sqrtf(wsum(s * s));
    qw[b * 256 + a * 64 + q] = s / (nrm + 1e-8f) * w[a];
}

// ---------- alpha: fp32 alpha (output, b-major) + bf16 alpha (b-major) ----------
__global__ __launch_bounds__(256) void alpha_kernel(
    const float* __restrict__ scores, const void* __restrict__ tau_p,
    const int* __restrict__ flags,
    float* __restrict__ alpha_out, unsigned short* __restrict__ alpha_bf)
{
    const int b = blockIdx.x;
    const int tid = threadIdx.x;
    const float tauv = ldin(tau_p, 0, flags[ITAU]);
    float ar[8];
    float lsum = 0.f;
#pragma unroll
    for (int i = 0; i < 8; i++) {
        int n = i * 256 + tid;
        float s = scores[b * 2048 + n];
        float g = 1.f / (1.f + expf(-(s - tauv)));  // LAMBDA_SHARP=1
        ar[i] = g * expf(s);                         // TEMPERATURE=1
        lsum += ar[i];
    }
    __shared__ float sb[4];
    float wsv = wsum(lsum);
    if ((tid & 63) == 0) sb[tid >> 6] = wsv;
    __syncthreads();
    float tot = sb[0] + sb[1] + sb[2] + sb[3];
    float inv = 1.f / (tot + 1e-8f);
#pragma unroll
    for (int i = 0; i < 8; i++) {
        int n = i * 256 + tid;
        float al = ar[i] * inv;
        alpha_out[b * 2048 + n] = al;
        alpha_bf[b * 2048 + n] = bfbits(al);
    }
}

// ---------- W_assembled via MFMA ----------
// C[b, c] = sum_n alphaB[b,n] * UV[n, c],  c = dl*8+el within the block's 8d x 8e tile.
// Block: 256 thr (4 waves); M_t=256 (all b), N_t=64, K-step=32; grid (32 dt, 32 et).
// UV generated on the fly into LDS in B-fragment order; frag blocks XOR-swizzled.
#define QS 136  // bf16 stride per (cg,quad) frag block (16 l16 x 8 j + 8 pad)
__global__ __launch_bounds__(256) void assemble_mfma(
    const unsigned short* __restrict__ alphaB,  // bf16 (256 b x 2048 n)
    const void* __restrict__ pool,
    const void* __restrict__ W_base,
    const int* __restrict__ flags,
    float* __restrict__ Wout)                   // (256,256,256) fp32
{
    const int fp = flags[IPOOL], fw = flags[IWBASE];
    const int dt = blockIdx.x, et = blockIdx.y;
    const int d0 = dt * 8, e0 = et * 8;
    const int t = threadIdx.x;
    const int w = t >> 6, l = t & 63;
    const int q = l >> 4, l16 = l & 15;

    // generator mapping: thread covers n-pair (np) x c-quad (cq)
    const int np = t >> 4;              // 0..15 -> k = np*2, np*2+1
    const int cq = t & 15;              // c = cq*4 + i
    const int dl = cq >> 1;
    const int el0 = (cq & 1) * 4;
    const int cgw = cq >> 2;            // c >> 4
    const int l16w0 = (cq & 3) * 4;     // c & 15 base
    const int kq = np >> 2;             // quad of k
    const int j0 = (np * 2) & 7;        // even
    const int pbw = cgw * 4 + (kq ^ cgw);

    __shared__ __align__(16) unsigned short uvb[2][16 * QS];

    f32x4 acc[4][4] = {};

    int p = 0;
    for (int step = 0; step < 64; step++) {
        const int n0 = step * 32;
        // ---- generate UV tile (32n x 64c) in bf16 into uvb[p] ----
        float uv0[4] = {0.f, 0.f, 0.f, 0.f};
        float uv1[4] = {0.f, 0.f, 0.f, 0.f};
        if (fp == 0) {
            const float* p0 = (const float*)pool + (size_t)(n0 + np * 2) * D_POOL;
            const float* p1 = p0 + D_POOL;
            float4 ua0 = *(const float4*)(p0 + (d0 + dl) * 8);
            float4 ub0 = *(const float4*)(p0 + (d0 + dl) * 8 + 4);
            float4 ua1 = *(const float4*)(p1 + (d0 + dl) * 8);
            float4 ub1 = *(const float4*)(p1 + (d0 + dl) * 8 + 4);
            float U0[8] = {ua0.x, ua0.y, ua0.z, ua0.w, ub0.x, ub0.y, ub0.z, ub0.w};
            float U1[8] = {ua1.x, ua1.y, ua1.z, ua1.w, ub1.x, ub1.y, ub1.z, ub1.w};
            const float* v0 = p0 + 2048 + e0 + el0;
            const float* v1 = p1 + 2048 + e0 + el0;
#pragma unroll
            for (int r = 0; r < 8; r++) {
                float4 w0 = *(const float4*)(v0 + r * 256);
                float4 w1 = *(const float4*)(v1 + r * 256);
                uv0[0] += U0[r] * w0.x; uv0[1] += U0[r] * w0.y;
                uv0[2] += U0[r] * w0.z; uv0[3] += U0[r] * w0.w;
                uv1[0] += U1[r] * w1.x; uv1[1] += U1[r] * w1.y;
                uv1[2] += U1[r] * w1.z; uv1[3] += U1[r] * w1.w;
            }
        } else {
            size_t pr0 = (size_t)(n0 + np * 2) * D_POOL;
            size_t pr1 = pr0 + D_POOL;
#pragma unroll
            for (int r = 0; r < 8; r++) {
                float u0 = ldin(pool, pr0 + (d0 + dl) * 8 + r, 1);
                float u1 = ldin(pool, pr1 + (d0 + dl) * 8 + r, 1);
#pragma unroll
                for (int i = 0; i < 4; i++) {
                    uv0[i] += u0 * ldin(pool, pr0 + 2048 + r * 256 + e0 + el0 + i, 1);
                    uv1[i] += u1 * ldin(pool, pr1 + 2048 + r * 256 + e0 + el0 + i, 1);
                }
            }
        }
#pragma unroll
        for (int i = 0; i < 4; i++) {
            unsigned pk = ((unsigned)bfbits(uv1[i]) << 16) | bfbits(uv0[i]);
            *(unsigned*)&uvb[p][pbw * QS + (l16w0 + i) * 8 + j0] = pk;
        }
        __syncthreads();
        // ---- consume: A-frags from global (L2-hot), B-frags from LDS, MFMA ----
        bf16x8 afr[4];
#pragma unroll
        for (int mt = 0; mt < 4; mt++) {
            const unsigned short* ap =
                alphaB + (size_t)(w * 64 + mt * 16 + l16) * 2048 + n0 + q * 8;
            afr[mt] = *(const bf16x8*)ap;
        }
        bf16x8 bfr[4];
#pragma unroll
        for (int cg = 0; cg < 4; cg++) {
            int pbr = cg * 4 + (q ^ cg);
            bfr[cg] = *(const bf16x8*)&uvb[p][pbr * QS + l16 * 8];
        }
#pragma unroll
        for (int mt = 0; mt < 4; mt++)
#pragma unroll
            for (int cg = 0; cg < 4; cg++)
                acc[mt][cg] = __builtin_amdgcn_mfma_f32_16x16x32_bf16(
                    afr[mt], bfr[cg], acc[mt][cg], 0, 0, 0);
        p ^= 1;
    }

    // ---- epilogue: += W_base, store fp32 ----
    float wb[4];
#pragma unroll
    for (int cg = 0; cg < 4; cg++) {
        int c = cg * 16 + l16;
        wb[cg] = ldin(W_base, (size_t)(d0 + (c >> 3)) * 256 + e0 + (c & 7), fw);
    }
#pragma unroll
    for (int mt = 0; mt < 4; mt++) {
#pragma unroll
        for (int cg = 0; cg < 4; cg++) {
            int c = cg * 16 + l16;
            size_t col = (size_t)(d0 + (c >> 3)) * 256 + e0 + (c & 7);
#pragma unroll
            for (int r = 0; r < 4; r++) {
                int b = w * 64 + mt * 16 + q * 4 + r;
                Wout[(size_t)b * 65536 + col] = acc[mt][cg][r] + wb[cg];
            }
        }
    }
}

// ---------- h_t + y (reads fp32 W_assembled) ----------
__global__ __launch_bounds__(256) void hty_kernel(
    const float* __restrict__ Wout, const float* __restrict__ hA,
    const float* __restrict__ bass, const void* __restrict__ gamma_p,
    const int* __restrict__ flags, float* __restrict__ y)
{
    const int b = blockIdx.y;
    const int c = blockIdx.x * 4 + (threadIdx.x >> 6);
    const int lane = threadIdx.x & 63;
    const float4 wv = ((const float4*)(Wout + ((size_t)b * 65536 + c * 256)))[lane];
    const float4 h4 = ((const float4*)(hA + b * 256))[lane];
    float s = wv.x * h4.x + wv.y * h4.y + wv.z * h4.z + wv.w * h4.w;
    s = wsum(s);
    if (lane == 0) {
        float ht = s + bass[b * 256 + c];
        y[b * 256 + c] = hA[b * 256 + c] + ldin(gamma_p, 0, flags[IGAMMA]) * ht;
    }
}

// ---------- layernorm ----------
__global__ __launch_bounds__(256) void ln_kernel(
    const float* __restrict__ y, const void* __restrict__ ln_scale,
    const void* __restrict__ ln_bias, const int* __restrict__ flags,
    float* __restrict__ hmid)
{
    const int fs = flags[ILNS], fb = flags[ILNB];
    const int b = blockIdx.x, tid = threadIdx.x;
    float v = y[b * 256 + tid];
    __shared__ float s1b[4], s2b[4];
    float w1 = wsum(v), w2 = wsum(v * v);
    if ((tid & 63) == 0) { s1b[tid >> 6] = w1; s2b[tid >> 6] = w2; }
    __syncthreads();
    float mu = (s1b[0] + s1b[1] + s1b[2] + s1b[3]) * (1.f / 256.f);
    float ex2 = (s2b[0] + s2b[1] + s2b[2] + s2b[3]) * (1.f / 256.f);
    float var = ex2 - mu * mu;
    float inv = 1.f / sqrtf(var + 1e-6f);
    hmid[b * 256 + tid] = (v - mu) * inv * ldin(ln_scale, tid, fs)
                        + ldin(ln_bias, tid, fb);
}

// ---------- launch ----------
extern "C" void kernel_launch(void* const* d_in, const int* in_sizes, int n_in,
                              void* d_out, int out_size, void* d_ws, size_t ws_size,
                              hipStream_t stream)
{
    (void)out_size; (void)n_in;
    const void* x      = d_in[0];
    const void* pool   = d_in[1];
    const void* A_w0   = d_in[2];
    const void* A_b0   = d_in[3];
    const void* A_w1   = d_in[4];
    const void* A_b1   = d_in[5];
    const void* W_Q    = d_in[6];
    const void* W_K    = d_in[7];
    const void* logits = d_in[8];
    const void* tau    = d_in[9];
    const void* W_base = d_in[10];
    const void* b_base = d_in[11];
    const void* gamma  = d_in[12];
    const void* ln_s   = d_in[13];
    const void* ln_b   = d_in[14];
    const void* B_w0   = d_in[15];
    const void* B_b0   = d_in[16];
    const void* B_w1   = d_in[17];
    const void* B_b1   = d_in[18];

    // Outputs: FP32, concatenated in return order.
    float* out       = (float*)d_out;
    float* out0      = out;               // (256,512)
    float* out_alpha = out + 131072;      // (256,2048)
    float* out_W     = out + 655360;      // (256,256,256)
    float* out_keys  = out + 17432576;    // (2048,4,64)

    // Small scratch, always in d_ws
    float* ws = (float*)d_ws;
    int*   flagp   = (int*)d_ws;          // ints [0,32)
    float* ws_w    = ws + 32;
    float* ws_hA   = ws + 64;             // 65536
    float* ws_qw   = ws + 65600;          // 65536
    float* ws_bass = ws + 131136;         // 65536
    float* ws_y    = ws + 196672;         // 65536
    float* ws_hmid = ws + 262208;         // 65536 -> 327744
    unsigned short* alpha_bf = (unsigned short*)(ws + 327744);  // 524288 bf16 = 262144 f32
    // small region ends at 589888 floats (2.36 MB)

    // Big slots: prefer d_ws; fall back to out_W region (dead until assemble).
    size_t wsf = ws_size / 4;
    bool full = wsf >= 1638464;
    float* slotA;   // G -> scores -> T1
    float* slotB;   // kn
    float* T1;
    float* scr = (float*)out_W;
    if (full) {
        slotA = ws + 589888;    // 524288
        slotB = ws + 1114176;   // 524288 -> 1638464 total
        T1    = slotA;
    } else {
        slotA = scr;
        slotB = scr + 524288;
        T1    = (float*)alpha_bf;  // alpha_bf dead after assemble; 262144 floats fits
    }
    float* G      = slotA;
    float* scores = slotA;
    float* kn     = slotB;

    // 0) per-input dtype detection
    P19 ip;
    for (int i = 0; i < 19; i++) { ip.p[i] = d_in[i]; ip.n[i] = in_sizes[i]; }
    detect_all<<<19, 256, 0, stream>>>(ip, flagp);
    // 1) aspect softmax
    softmax4_kernel<<<1, 64, 0, stream>>>(logits, flagp, ws_w);
    // 2) A-MLP
    gemm64<0><<<dim3(16, 4), 256, 0, stream>>>(
        x, 512, IX, A_w0, 1024, IAW0, 0, A_b0, IAB0,
        G, 1024, 256, 1024, 512, 1, flagp);
    gemm64<0><<<dim3(4, 4), 256, 0, stream>>>(
        G, 1024, -1, A_w1, 256, IAW1, 0, A_b1, IAB1,
        ws_hA, 256, 256, 256, 1024, 0, flagp);
    // 3) keys + normalize
    keys_kernel<<<dim3(4, 32), 256, 0, stream>>>(pool, W_K, flagp, out_keys, kn);
    // 4) queries
    queries_kernel<<<256, 256, 0, stream>>>(ws_hA, W_Q, flagp, ws_w, ws_qw);
    // 5) scores = qw @ kn^T
    gemm64<1><<<dim3(32, 4), 256, 0, stream>>>(
        ws_qw, 256, -1, kn, 256, -1, 0, nullptr, -1,
        scores, 2048, 256, 2048, 256, 0, flagp);
    // 6) alpha -> out_alpha (fp32) + alpha_bf (bf16 b-major)
    alpha_kernel<<<256, 256, 0, stream>>>(scores, tau, flagp, out_alpha, alpha_bf);
    // 7) b_assembled = alpha @ pool[:,4096:4352] + b_base (before assemble)
    gemm64<0><<<dim3(4, 4), 256, 0, stream>>>(
        out_alpha, 2048, -1, pool, 4608, IPOOL, 4096, b_base, IBBASE,
        ws_bass, 256, 256, 256, 2048, 0, flagp);
    // 8) W_assembled via MFMA (dominant)
    assemble_mfma<<<dim3(32, 32), 256, 0, stream>>>(alpha_bf, pool, W_base, flagp, out_W);
    // 9) h_t, y
    hty_kernel<<<dim3(64, 256), 256, 0, stream>>>(out_W, ws_hA, ws_bass, gamma, flagp, ws_y);
    // 10) layernorm
    ln_kernel<<<256, 256, 0, stream>>>(ws_y, ln_s, ln_b, flagp, ws_hmid);
    // 11) B-MLP
    gemm64<0><<<dim3(16, 4), 256, 0, stream>>>(
        ws_hmid, 256, -1, B_w0, 1024, IBW0, 0, B_b0, IBB0,
        T1, 1024, 256, 1024, 256, 1, flagp);
    gemm64<0><<<dim3(8, 4), 256, 0, stream>>>(
        T1, 1024, -1, B_w1, 512, IBW1, 0, B_b1, IBB1,
        out0, 512, 256, 512, 1024, 0, flagp);
}